// Round 12
// baseline (504.593 us; speedup 1.0000x reference)
//
#include <hip/hip_runtime.h>
#include <stdint.h>

// BitStackLinear. Device dtypes: x,u,vt = float32 (harness upcasts fp16),
// qweight = int32, out = float32.
// Pipeline: build_w ; 256x256 4-phase Gray-code bf16 GEMM (R9 schedule) with
// A-side f32->bf16 conversion FUSED into reg-staged A (kills convert_x pass).
// B staged via global_load_lds. T2 chunk-XOR swizzle, counted vmcnt/lgkm,
// setprio, XCD swizzle.

#define W_BITS 4
#define OUT_F  4096
#define IN_F   4096
#define K_RANK 16
#define M_TOT  8192
#define QW_PER_BIT (OUT_F * IN_F / 8)

typedef __attribute__((ext_vector_type(8))) short bf16x8;
typedef __attribute__((ext_vector_type(4))) float f32x4;

__device__ __forceinline__ unsigned short f2bf(float f) {
  union { float f; unsigned int u; } c; c.f = f;
  unsigned int r = c.u + 0x7fffu + ((c.u >> 16) & 1u);  // RNE
  return (unsigned short)(r >> 16);
}

__device__ __forceinline__ uint4 cvt8(f32x4 a, f32x4 b) {
  unsigned short o8[8] = {f2bf(a[0]), f2bf(a[1]), f2bf(a[2]), f2bf(a[3]),
                          f2bf(b[0]), f2bf(b[1]), f2bf(b[2]), f2bf(b[3])};
  return *reinterpret_cast<const uint4*>(o8);
}

// ---------------------------------------------------------------------------
// Kernel 1: w[o][i] = sum_bit sign * (u[bit] @ vt[bit])[o][i]; w bf16.
// ---------------------------------------------------------------------------
#define TO 4

__global__ __launch_bounds__(256) void build_w(
    const int*   __restrict__ qw,
    const float* __restrict__ u,
    const float* __restrict__ vt,
    unsigned short* __restrict__ w)
{
  const int tid = blockIdx.x * 256 + threadIdx.x;
  const int ig  = tid & 511;
  const int i0  = ig << 3;
  const int ob  = (tid >> 9) << 2;

  float acc[TO][8];
  #pragma unroll
  for (int t = 0; t < TO; ++t)
    #pragma unroll
    for (int ii = 0; ii < 8; ++ii) acc[t][ii] = 0.0f;

  #pragma unroll
  for (int bit = 0; bit < W_BITS; ++bit) {
    float lr[TO][8];
    #pragma unroll
    for (int t = 0; t < TO; ++t)
      #pragma unroll
      for (int ii = 0; ii < 8; ++ii) lr[t][ii] = 0.0f;

    const float* vbase = vt + (size_t)(bit * K_RANK) * IN_F + i0;
    const float* ubase = u + (size_t)(bit * OUT_F + ob) * K_RANK;

    #pragma unroll
    for (int k = 0; k < K_RANK; ++k) {
      const f32x4 v0 = *reinterpret_cast<const f32x4*>(vbase + (size_t)k * IN_F);
      const f32x4 v1 = *reinterpret_cast<const f32x4*>(vbase + (size_t)k * IN_F + 4);
      float vf[8] = {v0[0], v0[1], v0[2], v0[3], v1[0], v1[1], v1[2], v1[3]};
      #pragma unroll
      for (int t = 0; t < TO; ++t) {
        const float uk = ubase[t * K_RANK + k];
        #pragma unroll
        for (int ii = 0; ii < 8; ++ii) lr[t][ii] += uk * vf[ii];
      }
    }

    #pragma unroll
    for (int t = 0; t < TO; ++t) {
      const int q = qw[(size_t)bit * QW_PER_BIT + (size_t)(ob + t) * (IN_F / 8) + ig];
      #pragma unroll
      for (int ii = 0; ii < 8; ++ii)
        acc[t][ii] += ((q >> ii) & 1) ? lr[t][ii] : -lr[t][ii];
    }
  }

  #pragma unroll
  for (int t = 0; t < TO; ++t) {
    unsigned short o8[8];
    #pragma unroll
    for (int ii = 0; ii < 8; ++ii) o8[ii] = f2bf(acc[t][ii]);
    *reinterpret_cast<uint4*>(w + (size_t)(ob + t) * IN_F + i0) =
        *reinterpret_cast<const uint4*>(o8);
  }
}

// ---------------------------------------------------------------------------
// Kernel 2 (main): 256x256 tile, BK=64, 512 thr = 8 waves (2Mx4N).
// R9 Gray-code schedule (0,0)->(0,1)->(1,1)->(1,0), B-reg role swap (P/Q).
// A staged via regs (f32 load + cvt + ds_write, swizzle preserved), B via
// global_load_lds.
// vm ledger (groups of 6: ph1 = A0ld x4 + B0' x2; ph2 = A1ld x4 + B1' x2):
//   ph1 vmcnt(6): forces G2(prev) done -> B1(cur) ready for ph1-end reads.
//   ph2 vmcnt(6): forces G1(this) done -> B0'(next) + A0ld regs ready.
//   ph3 vmcnt(6): no-op (nothing new issued).
//   ph4 vmcnt(2): forces A1ld regs done for cvt.
// lgkm ledger (DS FIFO per wave):
//   ph1 lgkm(0): drains ph4(prev) trailing A0-next reads -> aF valid.
//   ph2 lgkm(0): drains ph1's B1 reads -> Q valid.
//   ph3 lgkm(0): drains ph2's A1 reads -> aF valid. Then: cvt A0 + 2 writes +
//     4 RD_B(next B0) + lgkm(4) -> writes drained pre-barrier (visibility).
//   ph4 lgkm(4): keeps ph3's 4 reads in flight. After MFMA: cvt A1 + 2 writes
//     + 8 RD_A(next A0, written ph3, barrier-separated) + lgkm(8) -> writes
//     drained pre-barrier.
// ---------------------------------------------------------------------------
__device__ __forceinline__ void gll16(unsigned short* lds, const unsigned short* g) {
  __builtin_amdgcn_global_load_lds(
      (const __attribute__((address_space(1))) unsigned int*)g,
      (__attribute__((address_space(3))) unsigned int*)lds,
      16, 0, 0);
}

__global__ __launch_bounds__(512, 2) void gemm_256(
    const float* __restrict__ X,             // [M_TOT][IN_F] f32
    const unsigned short* __restrict__ W,    // [OUT_F][IN_F] bf16
    float* __restrict__ out)                 // [M_TOT][OUT_F] f32
{
  __shared__ __align__(16) unsigned short Al[2][256][64];   // 64 KiB
  __shared__ __align__(16) unsigned short Bl[2][256][64];   // 64 KiB

  const int bid = blockIdx.x;                   // 512 blocks (32 x 16)
  const int swz = (bid & 7) * 64 + (bid >> 3);  // XCD-bijective (512%8==0)
  const int bm = swz >> 4;                      // 0..31
  const int bn = swz & 15;                      // 0..15

  const int tid  = threadIdx.x;
  const int lane = tid & 63;
  const int wid  = tid >> 6;     // 0..7
  const int wm   = wid >> 2;     // 0..1
  const int wn   = wid & 3;      // 0..3

  // staging geometry: row sr; physical chunk tid&7 holds logical chunk
  // lc = (tid&7)^(sr&7)  (T2 swizzle; +64 rows preserves sr&7)
  const int sr = tid >> 3;                      // 0..63
  const int lc = (tid & 7) ^ (sr & 7);          // logical 16B-chunk index

  // A: f32 source (reg-staged). per half-tile: rows sr, sr+64.
  const float* AgF = X + (size_t)(bm * 256 + sr) * IN_F + lc * 8;
  // B: bf16 source (gll16), pre-swizzled column.
  const unsigned short* Bbase = W + (size_t)(bn * 256 + sr) * IN_F + lc * 8;
  unsigned short* Alt = &Al[0][0][0] + tid * 8;   // linear dest
  unsigned short* Blt = &Bl[0][0][0] + tid * 8;

  // fragment reads (mfma_f32_16x16x32_bf16: lane l -> row l&15, k=(l>>4)*8..+7)
  const int fr  = lane & 15;
  const int sw0 = (((lane >> 4) ^ (fr & 7)) << 3);   // shorts; ks=1 adds ^32
  const int aRow = (wm * 16 + fr) * 64;
  const int bRow = (wn * 16 + fr) * 64;
  const unsigned short* Ar = &Al[0][0][0];
  const unsigned short* Br = &Bl[0][0][0];

  f32x4 acc[8][4];
  #pragma unroll
  for (int f = 0; f < 8; ++f)
    #pragma unroll
    for (int g = 0; g < 4; ++g)
      acc[f][g] = (f32x4){0.f, 0.f, 0.f, 0.f};

  // ---- staging macros ----
  // A loads for half h of tile tn -> 4 dwordx4 regs (r0..r3)
#define ALOAD(h_, tn_, r0_, r1_, r2_, r3_) do {                                        \
    const float* g_ = AgF + (size_t)((h_) * 128) * IN_F + (size_t)(tn_) * 64;          \
    r0_ = *reinterpret_cast<const f32x4*>(g_);                                         \
    r1_ = *reinterpret_cast<const f32x4*>(g_ + 4);                                     \
    r2_ = *reinterpret_cast<const f32x4*>(g_ + (size_t)64 * IN_F);                     \
    r3_ = *reinterpret_cast<const f32x4*>(g_ + (size_t)64 * IN_F + 4);                 \
  } while (0)

#define AWRITE(buf_, h_, r0_, r1_, r2_, r3_) do {                                      \
    *reinterpret_cast<uint4*>(Alt + (buf_) * 16384 + (h_) * 8192)        = cvt8(r0_, r1_); \
    *reinterpret_cast<uint4*>(Alt + (buf_) * 16384 + (h_) * 8192 + 4096) = cvt8(r2_, r3_); \
  } while (0)

  // B half nh of tile tn via gll16
#define BSTAGE(buf_, nh_, tn_) do {                                                    \
    const unsigned short* gs_ = Bbase + (size_t)((nh_) * 128) * IN_F                   \
        + (size_t)(tn_) * 64;                                                          \
    unsigned short* ld_ = Blt + (buf_) * 16384 + (nh_) * 8192;                         \
    gll16(ld_, gs_);                                                                   \
    gll16(ld_ + 4096, gs_ + (size_t)64 * IN_F);                                        \
  } while (0)

#define WAITBARN(n_) do {                                                              \
    asm volatile("s_waitcnt vmcnt(" #n_ ")" ::: "memory");                             \
    __builtin_amdgcn_s_barrier();                                                      \
    __builtin_amdgcn_sched_barrier(0);                                                 \
  } while (0)

#define LGKMW(n_) do {                                                                 \
    asm volatile("s_waitcnt lgkmcnt(" #n_ ")" ::: "memory");                           \
    __builtin_amdgcn_sched_barrier(0);                                                 \
  } while (0)

#define SB() __builtin_amdgcn_sched_barrier(0)

#define ENDPH() do {                                                                   \
    __builtin_amdgcn_sched_barrier(0);                                                 \
    __builtin_amdgcn_s_barrier();                                                      \
  } while (0)

#define RD_A(base_, mh_, f_, ks_)                                                      \
    aF[f_][ks_] = *reinterpret_cast<const bf16x8*>(                                    \
        Ar + (base_) + ((mh_) * 4 + (f_)) * 2048 + aRow + (((ks_) * 32) ^ sw0))

#define RD_B(dst_, base_, nh_, g_, ks_)                                                \
    dst_[g_][ks_] = *reinterpret_cast<const bf16x8*>(                                  \
        Br + (base_) + ((nh_) * 2 + (g_)) * 4096 + bRow + (((ks_) * 32) ^ sw0))

#define MF(mh_, nh_, f_, g_, ks_, bsrc_)                                               \
    acc[(mh_) * 4 + (f_)][(nh_) * 2 + (g_)] = __builtin_amdgcn_mfma_f32_16x16x32_bf16( \
        aF[f_][ks_], bsrc_[g_][ks_], acc[(mh_) * 4 + (f_)][(nh_) * 2 + (g_)], 0, 0, 0)

#define MF4(mh_, nh_, f_, bsrc_) do {                                                  \
    MF(mh_, nh_, f_, 0, 0, bsrc_); MF(mh_, nh_, f_, 0, 1, bsrc_);                      \
    MF(mh_, nh_, f_, 1, 0, bsrc_); MF(mh_, nh_, f_, 1, 1, bsrc_); } while (0)

#define KTILE(P_, Q_, CC_, OO_, tn_) do {                                              \
    const int cb_ = (CC_) * 16384, ob_ = (OO_) * 16384;                                \
    /* ph1: MFMA (0,0)=A0xP; issue A0ld(next)+B0'(next); reads Q<-B1(cur) */           \
    ALOAD(0, tn_, a0r0, a0r1, a0r2, a0r3);                                             \
    BSTAGE(OO_, 0, tn_);                                                               \
    WAITBARN(6);                                                                       \
    LGKMW(0);                                                                          \
    __builtin_amdgcn_s_setprio(1);                                                     \
    RD_B(Q_, cb_, 1, 0, 0); SB(); MF4(0, 0, 0, P_); SB();                              \
    RD_B(Q_, cb_, 1, 0, 1); SB(); MF4(0, 0, 1, P_); SB();                              \
    RD_B(Q_, cb_, 1, 1, 0); SB(); MF4(0, 0, 2, P_); SB();                              \
    RD_B(Q_, cb_, 1, 1, 1); SB(); MF4(0, 0, 3, P_);                                    \
    __builtin_amdgcn_s_setprio(0);                                                     \
    ENDPH();                                                                           \
    /* ph2: MFMA (0,1)=A0xQ; issue A1ld(next)+B1'(next); reads aF<-A1(cur) */          \
    ALOAD(1, tn_, a1r0, a1r1, a1r2, a1r3);                                             \
    BSTAGE(OO_, 1, tn_);                                                               \
    WAITBARN(6);                                                                       \
    LGKMW(0);                                                                          \
    __builtin_amdgcn_s_setprio(1);                                                     \
    MF4(0, 1, 0, Q_); SB(); RD_A(cb_, 1, 0, 0); RD_A(cb_, 1, 0, 1); SB();              \
    MF4(0, 1, 1, Q_); SB(); RD_A(cb_, 1, 1, 0); RD_A(cb_, 1, 1, 1); SB();              \
    MF4(0, 1, 2, Q_); SB(); RD_A(cb_, 1, 2, 0); RD_A(cb_, 1, 2, 1); SB();              \
    MF4(0, 1, 3, Q_); SB(); RD_A(cb_, 1, 3, 0); RD_A(cb_, 1, 3, 1);                    \
    __builtin_amdgcn_s_setprio(0);                                                     \
    ENDPH();                                                                           \
    /* ph3: MFMA (1,1)=A1xQ; then cvt+write A0'(next); trailing Q<-B0(next) */         \
    WAITBARN(6);                                                                       \
    LGKMW(0);                                                                          \
    __builtin_amdgcn_s_setprio(1);                                                     \
    MF4(1, 1, 0, Q_); MF4(1, 1, 1, Q_); MF4(1, 1, 2, Q_); MF4(1, 1, 3, Q_);            \
    __builtin_amdgcn_s_setprio(0);                                                     \
    SB();                                                                              \
    AWRITE(OO_, 0, a0r0, a0r1, a0r2, a0r3);                                            \
    SB();                                                                              \
    RD_B(Q_, ob_, 0, 0, 0); RD_B(Q_, ob_, 0, 0, 1);                                    \
    RD_B(Q_, ob_, 0, 1, 0); RD_B(Q_, ob_, 0, 1, 1);                                    \
    LGKMW(4);                                                                          \
    ENDPH();                                                                           \
    /* ph4: MFMA (1,0)=A1xP; then cvt+write A1'(next); trailing aF<-A0(next) */        \
    WAITBARN(2);                                                                       \
    LGKMW(4);                                                                          \
    __builtin_amdgcn_s_setprio(1);                                                     \
    MF4(1, 0, 0, P_); MF4(1, 0, 1, P_); MF4(1, 0, 2, P_); MF4(1, 0, 3, P_);            \
    __builtin_amdgcn_s_setprio(0);                                                     \
    SB();                                                                              \
    AWRITE(OO_, 1, a1r0, a1r1, a1r2, a1r3);                                            \
    SB();                                                                              \
    RD_A(ob_, 0, 0, 0); RD_A(ob_, 0, 0, 1); RD_A(ob_, 0, 1, 0); RD_A(ob_, 0, 1, 1);    \
    RD_A(ob_, 0, 2, 0); RD_A(ob_, 0, 2, 1); RD_A(ob_, 0, 3, 0); RD_A(ob_, 0, 3, 1);    \
    LGKMW(8);                                                                          \
    ENDPH();                                                                           \
  } while (0)

  bf16x8 aF[4][2], bF0[2][2], bF1[2][2];
  f32x4 a0r0, a0r1, a0r2, a0r3, a1r0, a1r1, a1r2, a1r3;

  // prologue: tile 0 -> A via regs, B via gll16; then pre-read aF(A0), bF0.
  ALOAD(0, 0, a0r0, a0r1, a0r2, a0r3);
  ALOAD(1, 0, a1r0, a1r1, a1r2, a1r3);
  BSTAGE(0, 0, 0);
  BSTAGE(0, 1, 0);
  asm volatile("s_waitcnt vmcnt(4)" ::: "memory");   // A loads done
  __builtin_amdgcn_sched_barrier(0);
  AWRITE(0, 0, a0r0, a0r1, a0r2, a0r3);
  AWRITE(0, 1, a1r0, a1r1, a1r2, a1r3);
  asm volatile("s_waitcnt vmcnt(0) lgkmcnt(0)" ::: "memory");  // B landed, writes done
  __builtin_amdgcn_s_barrier();
  __builtin_amdgcn_sched_barrier(0);
  RD_A(0, 0, 0, 0); RD_A(0, 0, 0, 1); RD_A(0, 0, 1, 0); RD_A(0, 0, 1, 1);
  RD_A(0, 0, 2, 0); RD_A(0, 0, 2, 1); RD_A(0, 0, 3, 0); RD_A(0, 0, 3, 1);
  RD_B(bF0, 0, 0, 0, 0); RD_B(bF0, 0, 0, 0, 1);
  RD_B(bF0, 0, 0, 1, 0); RD_B(bF0, 0, 0, 1, 1);

  #pragma unroll 1
  for (int Th = 0; Th < 32; ++Th) {
    const int T0 = 2 * Th;
    const int tnA = T0 + 1;                          // <= 63 always
    const int tnB = (T0 + 2 < 64) ? T0 + 2 : 63;     // clamp (dup, unread)
    KTILE(bF0, bF1, 0, 1, tnA);
    KTILE(bF1, bF0, 1, 0, tnB);
  }

  asm volatile("s_waitcnt vmcnt(0) lgkmcnt(0)" ::: "memory");

  // epilogue: D mapping col = lane&15, row = (lane>>4)*4 + j [m89]
  const int rsub = (lane >> 4) << 2;
  #pragma unroll
  for (int f = 0; f < 8; ++f) {
    const int row = bm * 256 + (f * 2 + wm) * 16 + rsub;
    #pragma unroll
    for (int g = 0; g < 4; ++g) {
      const int col = bn * 256 + (g * 4 + wn) * 16 + (lane & 15);
      float* op = out + (size_t)row * OUT_F + col;
      #pragma unroll
      for (int j = 0; j < 4; ++j) op[(size_t)j * OUT_F] = acc[f][g][j];
    }
  }
#undef ALOAD
#undef AWRITE
#undef BSTAGE
#undef WAITBARN
#undef LGKMW
#undef SB
#undef ENDPH
#undef RD_A
#undef RD_B
#undef MF
#undef MF4
#undef KTILE
}

// ---------------------------------------------------------------------------
extern "C" void kernel_launch(void* const* d_in, const int* in_sizes, int n_in,
                              void* d_out, int out_size, void* d_ws, size_t ws_size,
                              hipStream_t stream) {
  (void)in_sizes; (void)n_in; (void)out_size; (void)ws_size;

  const float* x  = (const float*)d_in[0];
  const int*   qw = (const int*)d_in[1];
  const float* u  = (const float*)d_in[2];
  const float* vt = (const float*)d_in[3];
  float* out = (float*)d_out;

  unsigned short* w = (unsigned short*)d_ws;   // bf16 [4096][4096] = 32MB

  build_w<<<dim3(2048), dim3(256), 0, stream>>>(qw, u, vt, w);
  gemm_256<<<dim3(512), dim3(512), 0, stream>>>(x, w, out);
}

// Round 13
// 355.431 us; speedup vs baseline: 1.4197x; 1.4197x over previous
//
#include <hip/hip_runtime.h>
#include <stdint.h>

// BitStackLinear. Device dtypes: x,u,vt = float32 (harness upcasts fp16),
// qweight = int32, out = float32.
// Pipeline: build_w ; convert_x ; 256x256 4-phase Gray-code bf16 GEMM.
// R13 = R9 schedule with ONE barrier per phase (ENDPH removed):
//   phase p: STAGE G_p ; vmcnt(4)+barrier ; lgkm(0) ; MFMA ; trailing reads.
// Ledger: stage order ph1:B0' ph2:A0' ph3:B1' ph4:A1'; every phase-end read
// targets the G_{p-2} group, which vmcnt(4) (<=2 groups outstanding) + the
// barrier guarantees landed collectively. Reads-after-MFMA keeps the LDS
// pipe serving next-phase operands while the MFMA pipe drains this phase.

#define W_BITS 4
#define OUT_F  4096
#define IN_F   4096
#define K_RANK 16
#define M_TOT  8192
#define QW_PER_BIT (OUT_F * IN_F / 8)

typedef __attribute__((ext_vector_type(8))) short bf16x8;
typedef __attribute__((ext_vector_type(4))) float f32x4;

__device__ __forceinline__ unsigned short f2bf(float f) {
  union { float f; unsigned int u; } c; c.f = f;
  unsigned int r = c.u + 0x7fffu + ((c.u >> 16) & 1u);  // RNE
  return (unsigned short)(r >> 16);
}

// ---------------------------------------------------------------------------
// Kernel 0: X f32 -> bf16
// ---------------------------------------------------------------------------
__global__ __launch_bounds__(256) void convert_x(
    const float* __restrict__ X, unsigned short* __restrict__ Xb, int n8)
{
  const int stride = gridDim.x * blockDim.x;
  for (int i = blockIdx.x * blockDim.x + threadIdx.x; i < n8; i += stride) {
    const f32x4 a = *reinterpret_cast<const f32x4*>(X + (size_t)i * 8);
    const f32x4 b = *reinterpret_cast<const f32x4*>(X + (size_t)i * 8 + 4);
    unsigned short o8[8] = {f2bf(a[0]), f2bf(a[1]), f2bf(a[2]), f2bf(a[3]),
                            f2bf(b[0]), f2bf(b[1]), f2bf(b[2]), f2bf(b[3])};
    *reinterpret_cast<uint4*>(Xb + (size_t)i * 8) = *reinterpret_cast<const uint4*>(o8);
  }
}

// ---------------------------------------------------------------------------
// Kernel 1: w[o][i] = sum_bit sign * (u[bit] @ vt[bit])[o][i]; w bf16.
// ---------------------------------------------------------------------------
#define TO 4

__global__ __launch_bounds__(256) void build_w(
    const int*   __restrict__ qw,
    const float* __restrict__ u,
    const float* __restrict__ vt,
    unsigned short* __restrict__ w)
{
  const int tid = blockIdx.x * 256 + threadIdx.x;
  const int ig  = tid & 511;
  const int i0  = ig << 3;
  const int ob  = (tid >> 9) << 2;

  float acc[TO][8];
  #pragma unroll
  for (int t = 0; t < TO; ++t)
    #pragma unroll
    for (int ii = 0; ii < 8; ++ii) acc[t][ii] = 0.0f;

  #pragma unroll
  for (int bit = 0; bit < W_BITS; ++bit) {
    float lr[TO][8];
    #pragma unroll
    for (int t = 0; t < TO; ++t)
      #pragma unroll
      for (int ii = 0; ii < 8; ++ii) lr[t][ii] = 0.0f;

    const float* vbase = vt + (size_t)(bit * K_RANK) * IN_F + i0;
    const float* ubase = u + (size_t)(bit * OUT_F + ob) * K_RANK;

    #pragma unroll
    for (int k = 0; k < K_RANK; ++k) {
      const f32x4 v0 = *reinterpret_cast<const f32x4*>(vbase + (size_t)k * IN_F);
      const f32x4 v1 = *reinterpret_cast<const f32x4*>(vbase + (size_t)k * IN_F + 4);
      float vf[8] = {v0[0], v0[1], v0[2], v0[3], v1[0], v1[1], v1[2], v1[3]};
      #pragma unroll
      for (int t = 0; t < TO; ++t) {
        const float uk = ubase[t * K_RANK + k];
        #pragma unroll
        for (int ii = 0; ii < 8; ++ii) lr[t][ii] += uk * vf[ii];
      }
    }

    #pragma unroll
    for (int t = 0; t < TO; ++t) {
      const int q = qw[(size_t)bit * QW_PER_BIT + (size_t)(ob + t) * (IN_F / 8) + ig];
      #pragma unroll
      for (int ii = 0; ii < 8; ++ii)
        acc[t][ii] += ((q >> ii) & 1) ? lr[t][ii] : -lr[t][ii];
    }
  }

  #pragma unroll
  for (int t = 0; t < TO; ++t) {
    unsigned short o8[8];
    #pragma unroll
    for (int ii = 0; ii < 8; ++ii) o8[ii] = f2bf(acc[t][ii]);
    *reinterpret_cast<uint4*>(w + (size_t)(ob + t) * IN_F + i0) =
        *reinterpret_cast<const uint4*>(o8);
  }
}

// ---------------------------------------------------------------------------
// Kernel 2 (main): 256x256 tile, BK=64, 512 thr = 8 waves (2Mx4N).
// Gray-code quadrants (0,0)->(0,1)->(1,1)->(1,0); B-reg role swap P/Q per
// tile (manual 2-body loop -> static registers).
// Per phase (ONE barrier): STAGE ; vmcnt(4)+barrier ; lgkm(0) ; setprio+MFMA ;
// trailing ds_reads for the NEXT phase.
// vm ledger (1 group = 2 gll16 per phase): at phase p's barrier, outstanding
// <= {G_{p-1}, G_p} -> G_{p-2} landed. Every phase-end read targets G_{p-2}:
//   ph1-end B1(cur)  <- staged ph3(T-1); ph2-end A1(cur) <- ph4(T-1);
//   ph3-end B0(next) <- ph1(T);          ph4-end A0(next) <- ph2(T).
// lgkm: each phase's lgkm(0) drains the previous phase's trailing reads.
// WAR (re-stage vs old readers) separated by >= 2 barriers everywhere.
// ---------------------------------------------------------------------------
__device__ __forceinline__ void gll16(unsigned short* lds, const unsigned short* g) {
  __builtin_amdgcn_global_load_lds(
      (const __attribute__((address_space(1))) unsigned int*)g,
      (__attribute__((address_space(3))) unsigned int*)lds,
      16, 0, 0);
}

__global__ __launch_bounds__(512, 2) void gemm_256(
    const unsigned short* __restrict__ X,    // [M_TOT][IN_F] bf16
    const unsigned short* __restrict__ W,    // [OUT_F][IN_F] bf16
    float* __restrict__ out)                 // [M_TOT][OUT_F] f32
{
  __shared__ __align__(16) unsigned short Al[2][256][64];   // 64 KiB
  __shared__ __align__(16) unsigned short Bl[2][256][64];   // 64 KiB

  const int bid = blockIdx.x;                   // 512 blocks (32 x 16)
  const int swz = (bid & 7) * 64 + (bid >> 3);  // XCD-bijective (512%8==0)
  const int bm = swz >> 4;                      // 0..31
  const int bn = swz & 15;                      // 0..15

  const int tid  = threadIdx.x;
  const int lane = tid & 63;
  const int wid  = tid >> 6;     // 0..7
  const int wm   = wid >> 2;     // 0..1
  const int wn   = wid & 3;      // 0..3

  // staging: row sr, physical chunk tid&7 holds logical chunk (tid&7)^(sr&7)
  const int sr = tid >> 3;                                  // 0..63
  const int sc = (((tid & 7) ^ (sr & 7)) << 3);             // shorts

  const unsigned short* Abase = X + (size_t)(bm * 256 + sr) * IN_F + sc;
  const unsigned short* Bbase = W + (size_t)(bn * 256 + sr) * IN_F + sc;
  unsigned short* Alt = &Al[0][0][0] + tid * 8;   // linear dest
  unsigned short* Blt = &Bl[0][0][0] + tid * 8;

  // fragment reads (mfma_f32_16x16x32_bf16: lane l -> row l&15, k=(l>>4)*8..+7)
  const int fr  = lane & 15;
  const int sw0 = (((lane >> 4) ^ (fr & 7)) << 3);   // shorts; ks=1 adds ^32
  const int aRow = (wm * 16 + fr) * 64;
  const int bRow = (wn * 16 + fr) * 64;
  const unsigned short* Ar = &Al[0][0][0];
  const unsigned short* Br = &Bl[0][0][0];

  f32x4 acc[8][4];
  #pragma unroll
  for (int f = 0; f < 8; ++f)
    #pragma unroll
    for (int g = 0; g < 4; ++g)
      acc[f][g] = (f32x4){0.f, 0.f, 0.f, 0.f};

  // half-tile h: 0 = A rows 0-127, 1 = A rows 128-255, 2 = B-h0, 3 = B-h1
#define STAGE(buf, h, tn_) do {                                                        \
    const unsigned short* gs_ = ((h) < 2 ? Abase : Bbase)                              \
        + (size_t)(((h) & 1) * 128) * IN_F + (size_t)(tn_) * 64;                       \
    unsigned short* ld_ = ((h) < 2 ? Alt : Blt) + (buf) * 16384 + ((h) & 1) * 8192;    \
    gll16(ld_, gs_);                                                                   \
    gll16(ld_ + 4096, gs_ + (size_t)64 * IN_F);                                        \
  } while (0)

#define WAITBAR() do {                                                                 \
    asm volatile("s_waitcnt vmcnt(4)" ::: "memory");                                   \
    __builtin_amdgcn_s_barrier();                                                      \
    __builtin_amdgcn_sched_barrier(0);                                                 \
  } while (0)

#define LGKMW(n_) do {                                                                 \
    asm volatile("s_waitcnt lgkmcnt(" #n_ ")" ::: "memory");                           \
    __builtin_amdgcn_sched_barrier(0);                                                 \
  } while (0)

#define SB() __builtin_amdgcn_sched_barrier(0)

#define RD_A(base_, mh_, f_, ks_)                                                      \
    aF[f_][ks_] = *reinterpret_cast<const bf16x8*>(                                    \
        Ar + (base_) + ((mh_) * 4 + (f_)) * 2048 + aRow + (((ks_) * 32) ^ sw0))

#define RD_B(dst_, base_, nh_, g_, ks_)                                                \
    dst_[g_][ks_] = *reinterpret_cast<const bf16x8*>(                                  \
        Br + (base_) + ((nh_) * 2 + (g_)) * 4096 + bRow + (((ks_) * 32) ^ sw0))

#define MF(mh_, nh_, f_, g_, ks_, bsrc_)                                               \
    acc[(mh_) * 4 + (f_)][(nh_) * 2 + (g_)] = __builtin_amdgcn_mfma_f32_16x16x32_bf16( \
        aF[f_][ks_], bsrc_[g_][ks_], acc[(mh_) * 4 + (f_)][(nh_) * 2 + (g_)], 0, 0, 0)

#define MF4(mh_, nh_, f_, bsrc_) do {                                                  \
    MF(mh_, nh_, f_, 0, 0, bsrc_); MF(mh_, nh_, f_, 0, 1, bsrc_);                      \
    MF(mh_, nh_, f_, 1, 0, bsrc_); MF(mh_, nh_, f_, 1, 1, bsrc_); } while (0)

#define KTILE(P_, Q_, CC_, OO_, tn_) do {                                              \
    const int cb_ = (CC_) * 16384, ob_ = (OO_) * 16384;                                \
    /* ph1: MFMA (0,0)=A0xP; trailing reads Q<-B1(cur). Stage B0'(next). */            \
    STAGE(OO_, 2, tn_);                                                                \
    WAITBAR();                                                                         \
    LGKMW(0);                                                                          \
    __builtin_amdgcn_s_setprio(1);                                                     \
    MF4(0, 0, 0, P_); MF4(0, 0, 1, P_); MF4(0, 0, 2, P_); MF4(0, 0, 3, P_);            \
    __builtin_amdgcn_s_setprio(0);                                                     \
    SB();                                                                              \
    RD_B(Q_, cb_, 1, 0, 0); RD_B(Q_, cb_, 1, 0, 1);                                    \
    RD_B(Q_, cb_, 1, 1, 0); RD_B(Q_, cb_, 1, 1, 1);                                    \
    /* ph2: MFMA (0,1)=A0xQ; trailing reads aF<-A1(cur). Stage A0'(next). */           \
    STAGE(OO_, 0, tn_);                                                                \
    WAITBAR();                                                                         \
    LGKMW(0);                                                                          \
    __builtin_amdgcn_s_setprio(1);                                                     \
    MF4(0, 1, 0, Q_); MF4(0, 1, 1, Q_); MF4(0, 1, 2, Q_); MF4(0, 1, 3, Q_);            \
    __builtin_amdgcn_s_setprio(0);                                                     \
    SB();                                                                              \
    RD_A(cb_, 1, 0, 0); RD_A(cb_, 1, 0, 1); RD_A(cb_, 1, 1, 0); RD_A(cb_, 1, 1, 1);    \
    RD_A(cb_, 1, 2, 0); RD_A(cb_, 1, 2, 1); RD_A(cb_, 1, 3, 0); RD_A(cb_, 1, 3, 1);    \
    /* ph3: MFMA (1,1)=A1xQ; trailing reads Q<-B0(next). Stage B1'(next). */           \
    STAGE(OO_, 3, tn_);                                                                \
    WAITBAR();                                                                         \
    LGKMW(0);                                                                          \
    __builtin_amdgcn_s_setprio(1);                                                     \
    MF4(1, 1, 0, Q_); MF4(1, 1, 1, Q_); MF4(1, 1, 2, Q_); MF4(1, 1, 3, Q_);            \
    __builtin_amdgcn_s_setprio(0);                                                     \
    SB();                                                                              \
    RD_B(Q_, ob_, 0, 0, 0); RD_B(Q_, ob_, 0, 0, 1);                                    \
    RD_B(Q_, ob_, 0, 1, 0); RD_B(Q_, ob_, 0, 1, 1);                                    \
    /* ph4: MFMA (1,0)=A1xP; trailing reads aF<-A0(next). Stage A1'(next). */          \
    STAGE(OO_, 1, tn_);                                                                \
    WAITBAR();                                                                         \
    LGKMW(0);                                                                          \
    __builtin_amdgcn_s_setprio(1);                                                     \
    MF4(1, 0, 0, P_); MF4(1, 0, 1, P_); MF4(1, 0, 2, P_); MF4(1, 0, 3, P_);            \
    __builtin_amdgcn_s_setprio(0);                                                     \
    SB();                                                                              \
    RD_A(ob_, 0, 0, 0); RD_A(ob_, 0, 0, 1); RD_A(ob_, 0, 1, 0); RD_A(ob_, 0, 1, 1);    \
    RD_A(ob_, 0, 2, 0); RD_A(ob_, 0, 2, 1); RD_A(ob_, 0, 3, 0); RD_A(ob_, 0, 3, 1);    \
  } while (0)

  // prologue: stage tile 0 (A0, B0, B1, A1); vmcnt(4) -> A0,B0 landed;
  // barrier; pre-read aF<-A0, bF0<-B0.
  STAGE(0, 0, 0);
  STAGE(0, 2, 0);
  STAGE(0, 3, 0);
  STAGE(0, 1, 0);
  asm volatile("s_waitcnt vmcnt(4)" ::: "memory");
  __builtin_amdgcn_s_barrier();
  __builtin_amdgcn_sched_barrier(0);

  bf16x8 aF[4][2], bF0[2][2], bF1[2][2];
  RD_A(0, 0, 0, 0); RD_A(0, 0, 0, 1); RD_A(0, 0, 1, 0); RD_A(0, 0, 1, 1);
  RD_A(0, 0, 2, 0); RD_A(0, 0, 2, 1); RD_A(0, 0, 3, 0); RD_A(0, 0, 3, 1);
  RD_B(bF0, 0, 0, 0, 0); RD_B(bF0, 0, 0, 0, 1);
  RD_B(bF0, 0, 0, 1, 0); RD_B(bF0, 0, 0, 1, 1);

  #pragma unroll 1
  for (int Th = 0; Th < 32; ++Th) {
    const int T0 = 2 * Th;
    const int tnA = T0 + 1;                          // <= 63 always
    const int tnB = (T0 + 2 < 64) ? T0 + 2 : 63;     // clamp (dup, unread)
    KTILE(bF0, bF1, 0, 1, tnA);
    KTILE(bF1, bF0, 1, 0, tnB);
  }

  asm volatile("s_waitcnt vmcnt(0) lgkmcnt(0)" ::: "memory");

  // epilogue: D mapping col = lane&15, row = (lane>>4)*4 + j [m89]
  const int rsub = (lane >> 4) << 2;
  #pragma unroll
  for (int f = 0; f < 8; ++f) {
    const int row = bm * 256 + (f * 2 + wm) * 16 + rsub;
    #pragma unroll
    for (int g = 0; g < 4; ++g) {
      const int col = bn * 256 + (g * 4 + wn) * 16 + (lane & 15);
      float* op = out + (size_t)row * OUT_F + col;
      #pragma unroll
      for (int j = 0; j < 4; ++j) op[(size_t)j * OUT_F] = acc[f][g][j];
    }
  }
#undef STAGE
#undef WAITBAR
#undef LGKMW
#undef SB
#undef RD_A
#undef RD_B
#undef MF
#undef MF4
#undef KTILE
}

// ---------------------------------------------------------------------------
// Fallback GEMM (round-4, passing): A f32 reg-staged+converted. ws < 96MB only.
// ---------------------------------------------------------------------------
#define BM 128
#define BN 128
#define BK 32

__device__ __forceinline__ uint4 cvt8(f32x4 a, f32x4 b) {
  unsigned short o8[8] = {f2bf(a[0]), f2bf(a[1]), f2bf(a[2]), f2bf(a[3]),
                          f2bf(b[0]), f2bf(b[1]), f2bf(b[2]), f2bf(b[3])};
  return *reinterpret_cast<const uint4*>(o8);
}

__global__ __launch_bounds__(256) void gemm_f32stage(
    const float* __restrict__ X,
    const unsigned short* __restrict__ W,
    float* __restrict__ out)
{
  __shared__ __align__(16) unsigned short As[BM * BK];
  __shared__ __align__(16) unsigned short Bs[BN * BK];

  const int nbn = OUT_F / BN;
  const int cpx = (M_TOT / BM) * nbn / 8;
  const int bid = blockIdx.x;
  const int swz = (bid & 7) * cpx + (bid >> 3);
  const int bm = swz / nbn;
  const int bn = swz % nbn;

  const int tid  = threadIdx.x;
  const int lane = tid & 63;
  const int wid  = tid >> 6;
  const int wm   = wid >> 1;
  const int wn   = wid & 1;
  const int srow = tid >> 2;
  const int scol = (tid & 3) << 3;

  const float*          Ag = X + (size_t)(bm * BM + srow) * IN_F + scol;
  const unsigned short* Bg = W + (size_t)(bn * BN + srow) * IN_F + scol;

  const int fr = lane & 15;
  const int fk = (lane >> 4) << 3;

  f32x4 acc[4][4];
  #pragma unroll
  for (int m = 0; m < 4; ++m)
    #pragma unroll
    for (int n = 0; n < 4; ++n)
      acc[m][n] = (f32x4){0.f, 0.f, 0.f, 0.f};

  for (int k0 = 0; k0 < IN_F; k0 += BK) {
    const f32x4 a0a = *reinterpret_cast<const f32x4*>(Ag + k0);
    const f32x4 a0b = *reinterpret_cast<const f32x4*>(Ag + k0 + 4);
    const f32x4 a1a = *reinterpret_cast<const f32x4*>(Ag + (size_t)64 * IN_F + k0);
    const f32x4 a1b = *reinterpret_cast<const f32x4*>(Ag + (size_t)64 * IN_F + k0 + 4);
    const uint4 b0  = *reinterpret_cast<const uint4*>(Bg + k0);
    const uint4 b1  = *reinterpret_cast<const uint4*>(Bg + (size_t)64 * IN_F + k0);

    __syncthreads();
    *reinterpret_cast<uint4*>(As + tid * 8)        = cvt8(a0a, a0b);
    *reinterpret_cast<uint4*>(As + 2048 + tid * 8) = cvt8(a1a, a1b);
    *reinterpret_cast<uint4*>(Bs + tid * 8)        = b0;
    *reinterpret_cast<uint4*>(Bs + 2048 + tid * 8) = b1;
    __syncthreads();

    bf16x8 af[4], bfv[4];
    #pragma unroll
    for (int m = 0; m < 4; ++m)
      af[m] = *reinterpret_cast<const bf16x8*>(&As[(wm * 64 + m * 16 + fr) * BK + fk]);
    #pragma unroll
    for (int n = 0; n < 4; ++n)
      bfv[n] = *reinterpret_cast<const bf16x8*>(&Bs[(wn * 64 + n * 16 + fr) * BK + fk]);

    #pragma unroll
    for (int m = 0; m < 4; ++m)
      #pragma unroll
      for (int n = 0; n < 4; ++n)
        acc[m][n] = __builtin_amdgcn_mfma_f32_16x16x32_bf16(af[m], bfv[n], acc[m][n], 0, 0, 0);
  }

  const int rsub = (lane >> 4) << 2;
  #pragma unroll
  for (int m = 0; m < 4; ++m) {
    #pragma unroll
    for (int n = 0; n < 4; ++n) {
      const int col = bn * BN + wn * 64 + n * 16 + (lane & 15);
      #pragma unroll
      for (int j = 0; j < 4; ++j) {
        const int row = bm * BM + wm * 64 + m * 16 + rsub + j;
        out[(size_t)row * OUT_F + col] = acc[m][n][j];
      }
    }
  }
}

// ---------------------------------------------------------------------------
extern "C" void kernel_launch(void* const* d_in, const int* in_sizes, int n_in,
                              void* d_out, int out_size, void* d_ws, size_t ws_size,
                              hipStream_t stream) {
  (void)in_sizes; (void)n_in; (void)out_size;

  const float* x  = (const float*)d_in[0];
  const int*   qw = (const int*)d_in[1];
  const float* u  = (const float*)d_in[2];
  const float* vt = (const float*)d_in[3];
  float* out = (float*)d_out;

  unsigned short* w = (unsigned short*)d_ws;                   // 32 MB
  const size_t W_BYTES  = (size_t)OUT_F * IN_F * 2;
  const size_t XB_BYTES = (size_t)M_TOT * IN_F * 2;

  build_w<<<dim3(2048), dim3(256), 0, stream>>>(qw, u, vt, w);

  if (ws_size >= W_BYTES + XB_BYTES) {
    unsigned short* xb = w + (size_t)OUT_F * IN_F;
    convert_x<<<dim3(2048), dim3(256), 0, stream>>>(x, xb, M_TOT * IN_F / 8);
    gemm_256<<<dim3(512), dim3(512), 0, stream>>>(xb, w, out);
  } else {
    gemm_f32stage<<<dim3(2048), dim3(256), 0, stream>>>(x, w, out);
  }
}